// Round 1
// baseline (382.352 us; speedup 1.0000x reference)
//
#include <hip/hip_runtime.h>

// Fused spatio-temporal GCN for MI355X (gfx950), fp32 (no fp32 MFMA -> vector ALU).
// T=128, N=256, H=4, EMB=16, IN_DIMS=5, HID=64.
//
// Pass structure (minimizes adjacency HBM traffic: adj_t, adj_s, adj_t = 268 MB):
//  K1: l1t[n,h,t,:]  = prelu((adj_t[n,h] @ tem[n]) @ W_t1^T)   -> packed into B_pack[t][h][n][*]
//      (h==0 blocks also copy the 5 'spa' feature cols of graph into B_pack cols 0..4)
//  K2: per (t,h): C = adj_s[t,h] @ B_pack[t][h]  (256x21, cols 0..4 spa, 8..23 l1t)
//      l1s -> B_pack2[n][h][t][:]   (layout K3 consumes)
//      Ht  -> Ht_f[n][t][h][:]      (final layout)
//  K3: per (n,h): Hs = prelu((adj_t[n,h] @ B_pack2[n][h]) @ W_s2^T), then fused
//      MLP (tanh + 2-way softmax) and blend with Ht_f -> out[n][t][h][:]
//
// B matrices are wave-uniform per k -> uniform (scalar/broadcast) loads; adjacency
// streamed row-per-lane with float4 (64B line reused over 4 consecutive iters).
// No LDS, no barriers.

#define T_DIM 128
#define N_DIM 256
#define H_DIM 4

// ---------------- K1 ----------------
__global__ __launch_bounds__(128) void k1_l1t(
    const float* __restrict__ graph, const float* __restrict__ adj_t,
    const float* __restrict__ W_t1, const float* __restrict__ a_t1,
    float* __restrict__ B_pack)
{
    const int n = blockIdx.x;
    const int h = blockIdx.y;
    const int t = threadIdx.x;  // output row (0..127)

    const float* arow = adj_t + (((n * H_DIM + h) * T_DIM + t) * (size_t)T_DIM);
    float acc[5] = {0.f, 0.f, 0.f, 0.f, 0.f};

    for (int k0 = 0; k0 < T_DIM; k0 += 4) {
        const float4 a4 = *(const float4*)(arow + k0);
        const float av[4] = {a4.x, a4.y, a4.z, a4.w};
#pragma unroll
        for (int kk = 0; kk < 4; ++kk) {
            const int k = k0 + kk;
            // tem[n][k][d] = graph[(k*N + n)*6 + 1 + d]  (wave-uniform address)
            const float* b = graph + (k * N_DIM + n) * 6 + 1;
            const float a = av[kk];
#pragma unroll
            for (int d = 0; d < 5; ++d) acc[d] = fmaf(a, b[d], acc[d]);
        }
    }

    const float alpha = a_t1[0];
    const int base = ((t * H_DIM + h) * N_DIM + n) * 24;
    float v[16];
#pragma unroll
    for (int e = 0; e < 16; ++e) {
        float s = 0.f;
#pragma unroll
        for (int d = 0; d < 5; ++d) s = fmaf(acc[d], W_t1[e * 5 + d], s);
        v[e] = (s >= 0.f) ? s : alpha * s;
    }
#pragma unroll
    for (int q = 0; q < 4; ++q)
        *(float4*)(B_pack + base + 8 + 4 * q) = make_float4(v[4*q], v[4*q+1], v[4*q+2], v[4*q+3]);

    if (h == 0) {
        // fill spa feature cols 0..4 for all 4 h slots of this (t, n)
#pragma unroll
        for (int hh = 0; hh < H_DIM; ++hh) {
            const int sb = ((t * H_DIM + hh) * N_DIM + n) * 24;
#pragma unroll
            for (int d = 0; d < 5; ++d)
                B_pack[sb + d] = graph[(t * N_DIM + n) * 6 + 1 + d];
        }
    }
}

// ---------------- K2 ----------------
__global__ __launch_bounds__(256) void k2_l1s_ht(
    const float* __restrict__ adj_s, const float* __restrict__ B_pack,
    const float* __restrict__ W_s1, const float* __restrict__ a_s1,
    const float* __restrict__ W_t2, const float* __restrict__ a_t2,
    float* __restrict__ B_pack2, float* __restrict__ Ht_f)
{
    const int t = blockIdx.x;
    const int h = blockIdx.y;
    const int n = threadIdx.x;  // output row (0..255)

    const float* arow = adj_s + (((t * H_DIM + h) * N_DIM + n) * (size_t)N_DIM);
    const float* bp = B_pack + (t * H_DIM + h) * (N_DIM * 24);

    float acc[21];
#pragma unroll
    for (int i = 0; i < 21; ++i) acc[i] = 0.f;

    for (int k0 = 0; k0 < N_DIM; k0 += 4) {
        const float4 a4 = *(const float4*)(arow + k0);
        const float av[4] = {a4.x, a4.y, a4.z, a4.w};
#pragma unroll
        for (int kk = 0; kk < 4; ++kk) {
            const float* b = bp + (k0 + kk) * 24;  // wave-uniform
            const float a = av[kk];
#pragma unroll
            for (int d = 0; d < 5; ++d) acc[d] = fmaf(a, b[d], acc[d]);
#pragma unroll
            for (int e = 0; e < 16; ++e) acc[5 + e] = fmaf(a, b[8 + e], acc[5 + e]);
        }
    }

    // l1s = prelu(C_spa @ W_s1^T) -> B_pack2[n][h][t][e]
    {
        const float alpha = a_s1[0];
        const int base = ((n * H_DIM + h) * T_DIM + t) * 16;
        float v[16];
#pragma unroll
        for (int e = 0; e < 16; ++e) {
            float s = 0.f;
#pragma unroll
            for (int d = 0; d < 5; ++d) s = fmaf(acc[d], W_s1[e * 5 + d], s);
            v[e] = (s >= 0.f) ? s : alpha * s;
        }
#pragma unroll
        for (int q = 0; q < 4; ++q)
            *(float4*)(B_pack2 + base + 4 * q) = make_float4(v[4*q], v[4*q+1], v[4*q+2], v[4*q+3]);
    }
    // Ht = prelu(C_l1t @ W_t2^T) -> Ht_f[n][t][h][e]
    {
        const float alpha = a_t2[0];
        const int base = ((n * T_DIM + t) * H_DIM + h) * 16;
        float v[16];
#pragma unroll
        for (int e = 0; e < 16; ++e) {
            float s = 0.f;
#pragma unroll
            for (int e2 = 0; e2 < 16; ++e2) s = fmaf(acc[5 + e2], W_t2[e * 16 + e2], s);
            v[e] = (s >= 0.f) ? s : alpha * s;
        }
#pragma unroll
        for (int q = 0; q < 4; ++q)
            *(float4*)(Ht_f + base + 4 * q) = make_float4(v[4*q], v[4*q+1], v[4*q+2], v[4*q+3]);
    }
}

// ---------------- K3 ----------------
__global__ __launch_bounds__(128) void k3_hs_mlp(
    const float* __restrict__ adj_t, const float* __restrict__ B_pack2,
    const float* __restrict__ W_s2, const float* __restrict__ a_s2,
    const float* __restrict__ Ht_f,
    const float* __restrict__ Wm1, const float* __restrict__ bm1,
    const float* __restrict__ Wm2, const float* __restrict__ bm2,
    float* __restrict__ out)
{
    const int n = blockIdx.x;
    const int h = blockIdx.y;
    const int t = threadIdx.x;  // output row (0..127)

    const float* arow = adj_t + (((n * H_DIM + h) * T_DIM + t) * (size_t)T_DIM);
    const float* bp = B_pack2 + (n * H_DIM + h) * (T_DIM * 16);

    float acc[16];
#pragma unroll
    for (int i = 0; i < 16; ++i) acc[i] = 0.f;

    for (int k0 = 0; k0 < T_DIM; k0 += 4) {
        const float4 a4 = *(const float4*)(arow + k0);
        const float av[4] = {a4.x, a4.y, a4.z, a4.w};
#pragma unroll
        for (int kk = 0; kk < 4; ++kk) {
            const float* b = bp + (k0 + kk) * 16;  // wave-uniform
            const float a = av[kk];
#pragma unroll
            for (int e = 0; e < 16; ++e) acc[e] = fmaf(a, b[e], acc[e]);
        }
    }

    // Hs = prelu(acc @ W_s2^T)
    float hs[16], ht[16];
    {
        const float alpha = a_s2[0];
#pragma unroll
        for (int e = 0; e < 16; ++e) {
            float s = 0.f;
#pragma unroll
            for (int e2 = 0; e2 < 16; ++e2) s = fmaf(acc[e2], W_s2[e * 16 + e2], s);
            hs[e] = (s >= 0.f) ? s : alpha * s;
        }
    }
    const int rowbase = ((n * T_DIM + t) * H_DIM + h) * 16;
    {
        const float* htp = Ht_f + rowbase;
#pragma unroll
        for (int q = 0; q < 4; ++q) {
            const float4 v = *(const float4*)(htp + 4 * q);
            ht[4*q] = v.x; ht[4*q+1] = v.y; ht[4*q+2] = v.z; ht[4*q+3] = v.w;
        }
    }

    // MLP: hvec = tanh(comb @ Wm1^T + bm1); z = hvec @ Wm2^T + bm2; 2-way softmax
    float z0 = bm2[0], z1 = bm2[1];
    for (int j = 0; j < 64; ++j) {
        float s = bm1[j];
        const float* w = Wm1 + j * 32;  // wave-uniform
#pragma unroll
        for (int i = 0; i < 16; ++i) s = fmaf(hs[i], w[i], s);
#pragma unroll
        for (int i = 0; i < 16; ++i) s = fmaf(ht[i], w[16 + i], s);
        const float hj = tanhf(s);
        z0 = fmaf(hj, Wm2[j], z0);
        z1 = fmaf(hj, Wm2[64 + j], z1);
    }
    const float w0 = 1.0f / (1.0f + expf(z1 - z0));  // softmax over 2 == sigmoid
    const float w1 = 1.0f - w0;

    float* op = out + rowbase;
#pragma unroll
    for (int q = 0; q < 4; ++q) {
        *(float4*)(op + 4 * q) = make_float4(
            fmaf(w0, hs[4*q+0], w1 * ht[4*q+0]),
            fmaf(w0, hs[4*q+1], w1 * ht[4*q+1]),
            fmaf(w0, hs[4*q+2], w1 * ht[4*q+2]),
            fmaf(w0, hs[4*q+3], w1 * ht[4*q+3]));
    }
}

extern "C" void kernel_launch(void* const* d_in, const int* in_sizes, int n_in,
                              void* d_out, int out_size, void* d_ws, size_t ws_size,
                              hipStream_t stream)
{
    const float* graph = (const float*)d_in[0];
    const float* adj_s = (const float*)d_in[1];
    const float* adj_t = (const float*)d_in[2];
    const float* W_s1  = (const float*)d_in[3];
    const float* a_s1  = (const float*)d_in[4];
    const float* W_s2  = (const float*)d_in[5];
    const float* a_s2  = (const float*)d_in[6];
    const float* W_t1  = (const float*)d_in[7];
    const float* a_t1  = (const float*)d_in[8];
    const float* W_t2  = (const float*)d_in[9];
    const float* a_t2  = (const float*)d_in[10];
    const float* Wm1   = (const float*)d_in[11];
    const float* bm1   = (const float*)d_in[12];
    const float* Wm2   = (const float*)d_in[13];
    const float* bm2   = (const float*)d_in[14];
    float* out = (float*)d_out;

    float* ws = (float*)d_ws;
    float* B_pack  = ws;                       // 512*256*24   = 3,145,728 f32 (12.6 MB)
    float* B_pack2 = B_pack + 512 * 256 * 24;  // 1024*128*16  = 2,097,152 f32 ( 8.4 MB)
    float* Ht_f    = B_pack2 + 1024 * 128 * 16;// 256*128*4*16 = 2,097,152 f32 ( 8.4 MB)

    k1_l1t   <<<dim3(N_DIM, H_DIM), T_DIM, 0, stream>>>(graph, adj_t, W_t1, a_t1, B_pack);
    k2_l1s_ht<<<dim3(T_DIM, H_DIM), N_DIM, 0, stream>>>(adj_s, B_pack, W_s1, a_s1, W_t2, a_t2,
                                                        B_pack2, Ht_f);
    k3_hs_mlp<<<dim3(N_DIM, H_DIM), T_DIM, 0, stream>>>(adj_t, B_pack2, W_s2, a_s2, Ht_f,
                                                        Wm1, bm1, Wm2, bm2, out);
}